// Round 1
// baseline (241.937 us; speedup 1.0000x reference)
//
#include <hip/hip_runtime.h>

#define S_LEN 4096
#define DIM 256
#define NB 4

using short8 = __attribute__((ext_vector_type(8))) short;
using bf16x8 = __attribute__((ext_vector_type(8))) __bf16;
using f32x4  = __attribute__((ext_vector_type(4))) float;

__device__ inline unsigned short f2bf(float f) {
  unsigned int u = __builtin_bit_cast(unsigned int, f);
  u += 0x7FFFu + ((u >> 16) & 1u);
  return (unsigned short)(u >> 16);
}

__device__ inline f32x4 mfma16(short8 a, short8 b, f32x4 c) {
  return __builtin_amdgcn_mfma_f32_16x16x32_bf16(
      __builtin_bit_cast(bf16x8, a), __builtin_bit_cast(bf16x8, b), c, 0, 0, 0);
}

// ---------------- bias tables ----------------
__global__ void pow_kernel(float* __restrict__ pow_tab) {
  int i = blockIdx.x * 256 + threadIdx.x;
  if (i < S_LEN) pow_tab[i] = powf((float)i + 1e-9f, -1.4f);
}

__global__ void rowsum_kernel(const float* __restrict__ pow_tab, float* __restrict__ crow) {
  int tr = blockIdx.x;
  int tid = threadIdx.x;
  float s = 0.f;
  for (int i = tid; i < S_LEN; i += 256) s += pow_tab[abs(tr - i)];
  for (int off = 32; off; off >>= 1) s += __shfl_down(s, off, 64);
  __shared__ float red[4];
  if ((tid & 63) == 0) red[tid >> 6] = s;
  __syncthreads();
  if (tid == 0) crow[tr] = 1e-9f * (red[0] + red[1] + red[2] + red[3]);
}

// ---------------- Q/K projection: [16384,256] x W^T, bf16 out ----------------
// Q is pre-scaled by 1/16 (exact power of two).
__global__ __launch_bounds__(256, 1) void proj_qk_kernel(
    const float* __restrict__ x, const float* __restrict__ Wq, const float* __restrict__ bq,
    const float* __restrict__ Wk, const float* __restrict__ bk,
    unsigned short* __restrict__ Qs, unsigned short* __restrict__ Kb) {
  __shared__ unsigned short xt[64 * 264];  // x tile, padded stride
  __shared__ unsigned short wt[64 * 264];  // weight tile
  int t = threadIdx.x;
  int lane = t & 63, wid = t >> 6, c = lane & 15, g = lane >> 4;
  int m0 = blockIdx.x * 64;

  // stage x tile (fp32 -> bf16)
#pragma unroll
  for (int i = 0; i < 16; ++i) {
    int cc = t + i * 256;
    int row = cc >> 6, f4 = cc & 63;
    float4 v = *reinterpret_cast<const float4*>(x + (size_t)(m0 + row) * DIM + f4 * 4);
    ushort4 h;
    h.x = f2bf(v.x); h.y = f2bf(v.y); h.z = f2bf(v.z); h.w = f2bf(v.w);
    *reinterpret_cast<ushort4*>(&xt[row * 264 + f4 * 4]) = h;
  }

  for (int wm = 0; wm < 2; ++wm) {
    const float* W = wm ? Wk : Wq;
    const float* bias = wm ? bk : bq;
    unsigned short* dst = wm ? Kb : Qs;
    float scl = wm ? 1.0f : 0.0625f;
    for (int et = 0; et < 4; ++et) {
      int e0 = et * 64;
      __syncthreads();  // previous compute done before overwriting wt
#pragma unroll
      for (int i = 0; i < 16; ++i) {
        int cc = t + i * 256;
        int row = cc >> 6, f4 = cc & 63;
        float4 v = *reinterpret_cast<const float4*>(W + (size_t)(e0 + row) * DIM + f4 * 4);
        ushort4 h;
        h.x = f2bf(v.x); h.y = f2bf(v.y); h.z = f2bf(v.z); h.w = f2bf(v.w);
        *reinterpret_cast<ushort4*>(&wt[row * 264 + f4 * 4]) = h;
      }
      __syncthreads();
      f32x4 acc[4];
#pragma unroll
      for (int n = 0; n < 4; ++n) { acc[n][0] = 0.f; acc[n][1] = 0.f; acc[n][2] = 0.f; acc[n][3] = 0.f; }
#pragma unroll
      for (int kk = 0; kk < 8; ++kk) {
        short8 a = *reinterpret_cast<const short8*>(&xt[(wid * 16 + c) * 264 + kk * 32 + g * 8]);
#pragma unroll
        for (int n = 0; n < 4; ++n) {
          short8 b = *reinterpret_cast<const short8*>(&wt[(n * 16 + c) * 264 + kk * 32 + g * 8]);
          acc[n] = mfma16(a, b, acc[n]);
        }
      }
#pragma unroll
      for (int n = 0; n < 4; ++n) {
        int col = e0 + n * 16 + c;
        float bvv = bias[col];
#pragma unroll
        for (int r = 0; r < 4; ++r) {
          int rowm = m0 + wid * 16 + g * 4 + r;
          dst[(size_t)rowm * DIM + col] = f2bf((acc[n][r] + bvv) * scl);
        }
      }
    }
  }
}

// ---------------- V^T projection: VT[b][e][s] = Wv[e,:] . x[s,:] + bv[e] ----------------
__global__ __launch_bounds__(256, 1) void proj_vt_kernel(
    const float* __restrict__ x, const float* __restrict__ Wv, const float* __restrict__ bv,
    unsigned short* __restrict__ VTb) {
  __shared__ unsigned short wt[64 * 264];  // Wv rows (e)
  __shared__ unsigned short xt[64 * 264];  // x rows (s)
  int t = threadIdx.x;
  int lane = t & 63, wid = t >> 6, c = lane & 15, g = lane >> 4;
  int s0g = blockIdx.x * 64;    // global row of x
  int e0 = blockIdx.y * 64;
  int batch = s0g >> 12;
  int sin = s0g & 4095;

#pragma unroll
  for (int i = 0; i < 16; ++i) {
    int cc = t + i * 256;
    int row = cc >> 6, f4 = cc & 63;
    float4 v = *reinterpret_cast<const float4*>(Wv + (size_t)(e0 + row) * DIM + f4 * 4);
    ushort4 h;
    h.x = f2bf(v.x); h.y = f2bf(v.y); h.z = f2bf(v.z); h.w = f2bf(v.w);
    *reinterpret_cast<ushort4*>(&wt[row * 264 + f4 * 4]) = h;
  }
#pragma unroll
  for (int i = 0; i < 16; ++i) {
    int cc = t + i * 256;
    int row = cc >> 6, f4 = cc & 63;
    float4 v = *reinterpret_cast<const float4*>(x + (size_t)(s0g + row) * DIM + f4 * 4);
    ushort4 h;
    h.x = f2bf(v.x); h.y = f2bf(v.y); h.z = f2bf(v.z); h.w = f2bf(v.w);
    *reinterpret_cast<ushort4*>(&xt[row * 264 + f4 * 4]) = h;
  }
  __syncthreads();
  f32x4 acc[4];
#pragma unroll
  for (int n = 0; n < 4; ++n) { acc[n][0] = 0.f; acc[n][1] = 0.f; acc[n][2] = 0.f; acc[n][3] = 0.f; }
#pragma unroll
  for (int kk = 0; kk < 8; ++kk) {
    short8 a = *reinterpret_cast<const short8*>(&wt[(wid * 16 + c) * 264 + kk * 32 + g * 8]);
#pragma unroll
    for (int n = 0; n < 4; ++n) {
      short8 b = *reinterpret_cast<const short8*>(&xt[(n * 16 + c) * 264 + kk * 32 + g * 8]);
      acc[n] = mfma16(a, b, acc[n]);
    }
  }
  unsigned short* dst = VTb + (size_t)batch * DIM * S_LEN;
#pragma unroll
  for (int r = 0; r < 4; ++r) {
    int e = e0 + wid * 16 + g * 4 + r;
    float bvv = bv[e];
#pragma unroll
    for (int n = 0; n < 4; ++n) {
      dst[(size_t)e * S_LEN + sin + n * 16 + c] = f2bf(acc[n][r] + bvv);
    }
  }
}

// ---------------- flash attention ----------------
// block = 4 waves, QBLK=64 (16 q-rows/wave), KVBLK=64, D=256.
// p = exp(score - m) * (pow_tab[|q-k|] + 1e-9*rowsum_q)   (1/rowsum cancels in softmax)
__global__ __launch_bounds__(256, 1) void attn_kernel(
    const unsigned short* __restrict__ Qs, const unsigned short* __restrict__ Kb,
    const unsigned short* __restrict__ VTb, const float* __restrict__ pow_tab,
    const float* __restrict__ crow, float* __restrict__ out) {
  __shared__ unsigned short k_lds[64 * 264];    // K tile [64][256], padded stride
  __shared__ unsigned short vt_lds[256 * 80];   // V^T tile [256][64], padded stride
  __shared__ unsigned short p_lds[4 * 16 * 88]; // per-wave P tile [16][64], padded stride

  // XCD-aware swizzle: batch b -> XCDs {2b,2b+1}; its 4MB K+VT set stays L2-resident.
  int raw = blockIdx.x;
  int xcd = raw & 7;
  int idx = raw >> 3;
  int batch = xcd >> 1;
  int qtile = idx * 2 + (xcd & 1);
  int q0 = qtile * 64;

  int t = threadIdx.x;
  int lane = t & 63, wid = t >> 6, c = lane & 15, g = lane >> 4;

  const unsigned short* qg = Qs + (size_t)batch * S_LEN * DIM + (size_t)q0 * DIM;
  const unsigned short* kg = Kb + (size_t)batch * S_LEN * DIM;
  const unsigned short* vtg = VTb + (size_t)batch * DIM * S_LEN;

  // stage Q tile through k_lds, pull fragments to registers
#pragma unroll
  for (int i = 0; i < 8; ++i) {
    int cc = t + i * 256;
    int row = cc >> 5, ch = cc & 31;
    *reinterpret_cast<short8*>(&k_lds[row * 264 + ch * 8]) =
        *reinterpret_cast<const short8*>(qg + row * DIM + ch * 8);
  }
  __syncthreads();
  short8 qf[8];
  {
    int arow = wid * 16 + c;
#pragma unroll
    for (int kk = 0; kk < 8; ++kk)
      qf[kk] = *reinterpret_cast<const short8*>(&k_lds[arow * 264 + kk * 32 + g * 8]);
  }
  int qglob[4];
  float crq[4];
#pragma unroll
  for (int r = 0; r < 4; ++r) {
    qglob[r] = q0 + wid * 16 + g * 4 + r;
    crq[r] = crow[qglob[r]];
  }
  float mst[4] = {-1e30f, -1e30f, -1e30f, -1e30f};
  float lst[4] = {0.f, 0.f, 0.f, 0.f};
  f32x4 acc[16];
#pragma unroll
  for (int n = 0; n < 16; ++n) { acc[n][0] = 0.f; acc[n][1] = 0.f; acc[n][2] = 0.f; acc[n][3] = 0.f; }

  for (int kv = 0; kv < 64; ++kv) {
    int kv0 = kv * 64;
    __syncthreads();  // all waves done with previous K/VT tiles (and qf reads at kv==0)
#pragma unroll
    for (int i = 0; i < 8; ++i) {
      int cc = t + i * 256;
      int row = cc >> 5, ch = cc & 31;
      *reinterpret_cast<short8*>(&k_lds[row * 264 + ch * 8]) =
          *reinterpret_cast<const short8*>(kg + (size_t)(kv0 + row) * DIM + ch * 8);
    }
#pragma unroll
    for (int i = 0; i < 8; ++i) {
      int cc = t + i * 256;
      int row = cc >> 3, ch = cc & 7;
      *reinterpret_cast<short8*>(&vt_lds[row * 80 + ch * 8]) =
          *reinterpret_cast<const short8*>(vtg + (size_t)row * S_LEN + kv0 + ch * 8);
    }
    __syncthreads();

    // QK^T: sc[n][r] = score[q_local=g*4+r][kv_local=n*16+c]
    f32x4 sc[4];
#pragma unroll
    for (int n = 0; n < 4; ++n) { sc[n][0] = 0.f; sc[n][1] = 0.f; sc[n][2] = 0.f; sc[n][3] = 0.f; }
#pragma unroll
    for (int kk = 0; kk < 8; ++kk) {
#pragma unroll
      for (int n = 0; n < 4; ++n) {
        short8 b = *reinterpret_cast<const short8*>(&k_lds[(n * 16 + c) * 264 + kk * 32 + g * 8]);
        sc[n] = mfma16(qf[kk], b, sc[n]);
      }
    }

    // online softmax (m tracks raw scores; multiplicative bias weight)
    float mnew[4], scal[4];
#pragma unroll
    for (int r = 0; r < 4; ++r) {
      float mv = fmaxf(fmaxf(sc[0][r], sc[1][r]), fmaxf(sc[2][r], sc[3][r]));
#pragma unroll
      for (int off = 1; off < 16; off <<= 1) mv = fmaxf(mv, __shfl_xor(mv, off, 64));
      mnew[r] = fmaxf(mst[r], mv);
      scal[r] = __expf(mst[r] - mnew[r]);
      lst[r] *= scal[r];
      mst[r] = mnew[r];
    }
#pragma unroll
    for (int n = 0; n < 16; ++n) {
      acc[n][0] *= scal[0]; acc[n][1] *= scal[1]; acc[n][2] *= scal[2]; acc[n][3] *= scal[3];
    }
    float psum[4] = {0.f, 0.f, 0.f, 0.f};
#pragma unroll
    for (int n = 0; n < 4; ++n) {
#pragma unroll
      for (int r = 0; r < 4; ++r) {
        int kvgl = kv0 + n * 16 + c;
        int dd = abs(qglob[r] - kvgl);
        float w = pow_tab[dd] + crq[r];
        float p = __expf(sc[n][r] - mnew[r]) * w;
        psum[r] += p;
        p_lds[wid * 1408 + (g * 4 + r) * 88 + n * 16 + c] = f2bf(p);
      }
    }
#pragma unroll
    for (int r = 0; r < 4; ++r) {
      float sv = psum[r];
#pragma unroll
      for (int off = 1; off < 16; off <<= 1) sv += __shfl_xor(sv, off, 64);
      lst[r] += sv;
    }

    // PV: acc[n][r] += P[q_local][kv] * VT[d][kv]
#pragma unroll
    for (int kk = 0; kk < 2; ++kk) {
      short8 pa = *reinterpret_cast<const short8*>(&p_lds[wid * 1408 + c * 88 + kk * 32 + g * 8]);
#pragma unroll
      for (int n = 0; n < 16; ++n) {
        short8 vb = *reinterpret_cast<const short8*>(&vt_lds[(n * 16 + c) * 80 + kk * 32 + g * 8]);
        acc[n] = mfma16(pa, vb, acc[n]);
      }
    }
  }

  float* og = out + (size_t)batch * S_LEN * DIM;
#pragma unroll
  for (int r = 0; r < 4; ++r) {
    float inv = 1.0f / lst[r];
#pragma unroll
    for (int n = 0; n < 16; ++n) {
      og[(size_t)qglob[r] * DIM + n * 16 + c] = acc[n][r] * inv;
    }
  }
}

extern "C" void kernel_launch(void* const* d_in, const int* in_sizes, int n_in,
                              void* d_out, int out_size, void* d_ws, size_t ws_size,
                              hipStream_t stream) {
  const float* x  = (const float*)d_in[0];
  const float* Wq = (const float*)d_in[1];
  const float* bq = (const float*)d_in[2];
  const float* Wk = (const float*)d_in[3];
  const float* bk = (const float*)d_in[4];
  const float* Wv = (const float*)d_in[5];
  const float* bv = (const float*)d_in[6];
  float* out = (float*)d_out;

  char* ws = (char*)d_ws;
  unsigned short* Qs  = (unsigned short*)(ws);                              // 8 MB bf16 (pre-scaled 1/16)
  unsigned short* Kb  = (unsigned short*)(ws + (size_t)8 * 1024 * 1024);    // 8 MB bf16
  unsigned short* VTb = (unsigned short*)(ws + (size_t)16 * 1024 * 1024);   // 8 MB bf16, transposed
  float* pow_tab = (float*)(ws + (size_t)24 * 1024 * 1024);                 // 16 KB
  float* crow    = (float*)(ws + (size_t)24 * 1024 * 1024 + 16384);         // 16 KB

  hipLaunchKernelGGL(pow_kernel, dim3(16), dim3(256), 0, stream, pow_tab);
  hipLaunchKernelGGL(rowsum_kernel, dim3(4096), dim3(256), 0, stream, pow_tab, crow);
  hipLaunchKernelGGL(proj_qk_kernel, dim3(256), dim3(256), 0, stream, x, Wq, bq, Wk, bk, Qs, Kb);
  hipLaunchKernelGGL(proj_vt_kernel, dim3(256, 4), dim3(256), 0, stream, x, Wv, bv, VTb);
  hipLaunchKernelGGL(attn_kernel, dim3(256), dim3(256), 0, stream, Qs, Kb, VTb, pow_tab, crow, out);
}